// Round 1
// baseline (401.588 us; speedup 1.0000x reference)
//
#include <hip/hip_runtime.h>
#include <stdint.h>

#define N_TOK 4096
#define C_DIM 256

typedef __attribute__((ext_vector_type(8))) short short8;
typedef __attribute__((ext_vector_type(8))) _Float16 half8;
typedef __attribute__((ext_vector_type(4))) float floatx4;
typedef __attribute__((ext_vector_type(4))) unsigned short ushort4v;

__device__ __forceinline__ unsigned short bf16_rne(float f) {
    union { float f; unsigned int u; } v; v.f = f;
    unsigned int u = v.u;
    unsigned int rounded = u + 0x7FFFu + ((u >> 16) & 1u);
    return (unsigned short)(rounded >> 16);
}
__device__ __forceinline__ float bf16_to_f(unsigned short h) {
    union { unsigned int u; float f; } v; v.u = ((unsigned int)h) << 16;
    return v.f;
}
__device__ __forceinline__ void split_bf16(float f, unsigned short& h, unsigned short& l) {
    h = bf16_rne(f);
    l = bf16_rne(f - bf16_to_f(h));
}
__device__ __forceinline__ unsigned short f2h(float f) {
    union { _Float16 h; unsigned short u; } v; v.h = (_Float16)f; return v.u;
}
__device__ __forceinline__ float h2f(unsigned short u) {
    union { unsigned short u; _Float16 h; } v; v.u = u; return (float)v.h;
}
// pack two floats -> half2 (RNE, matches previous f2h-based error profile)
__device__ __forceinline__ unsigned int pack2h(float a, float b) {
    union { _Float16 h[2]; unsigned int u; } v;
    v.h[0] = (_Float16)a; v.h[1] = (_Float16)b;
    return v.u;
}
// async global->LDS 16B/lane; LDS dest = wave-uniform base + lane*16
__device__ __forceinline__ void g2l16(const void* g, void* l) {
    __builtin_amdgcn_global_load_lds(
        (const __attribute__((address_space(1))) void*)g,
        (__attribute__((address_space(3))) void*)l, 16, 0, 0);
}

// ---------------------------------------------------------------------------
// prep_kernel: one-time split/transpose (bf16 hi/lo pairs for fp32-accurate
// projection GEMM).  (unchanged)
// ---------------------------------------------------------------------------
__global__ __launch_bounds__(256) void prep_kernel(
    const float* __restrict__ x,
    const float* __restrict__ Wq, const float* __restrict__ Wk, const float* __restrict__ Wv,
    unsigned short* __restrict__ Xhi, unsigned short* __restrict__ Xlo,
    unsigned short* __restrict__ Whi, unsigned short* __restrict__ Wlo)
{
    const int t = threadIdx.x;
    if (blockIdx.x >= 1024) {
        const int pj = blockIdx.x - 1024;
        const float* W = (pj == 0) ? Wq : (pj == 1) ? Wk : Wv;
        unsigned short* dh = Whi + pj * 65536;
        unsigned short* dl = Wlo + pj * 65536;
        for (int it = 0; it < 64; it++) {
            const int idx = it * 1024 + t * 4;
            const float4 w = *(const float4*)&W[idx];
            unsigned short h0, l0, h1, l1, h2, l2, h3, l3;
            split_bf16(w.x, h0, l0); split_bf16(w.y, h1, l1);
            split_bf16(w.z, h2, l2); split_bf16(w.w, h3, l3);
            ushort4v vh; vh[0] = h0; vh[1] = h1; vh[2] = h2; vh[3] = h3;
            ushort4v vl; vl[0] = l0; vl[1] = l1; vl[2] = l2; vl[3] = l3;
            *(ushort4v*)&dh[idx] = vh;
            *(ushort4v*)&dl[idx] = vl;
        }
        return;
    }
    __shared__ float Xs[64 * 65];   // pitch 65: conflict-free transpose
    const int b  = blockIdx.x >> 8;
    const int ct = (blockIdx.x >> 6) & 3;
    const int nt = blockIdx.x & 63;
    const int c0 = ct * 64, n0 = nt * 64;
    {
        const int nch = t & 15, cr = t >> 4;
#pragma unroll
        for (int pass = 0; pass < 4; pass++) {
            const int c = pass * 16 + cr;
            const float4 v = *(const float4*)&x[((size_t)(b * C_DIM + c0 + c)) * N_TOK + n0 + nch * 4];
            float* row = &Xs[c * 65 + nch * 4];
            row[0] = v.x; row[1] = v.y; row[2] = v.z; row[3] = v.w;
        }
    }
    __syncthreads();
    {
        const int n = t >> 2, cc = t & 3;
        short8 vh0, vl0, vh1, vl1;
#pragma unroll
        for (int i = 0; i < 8; i++) {
            unsigned short h, l;
            split_bf16(Xs[(cc * 16 + i) * 65 + n], h, l);
            vh0[i] = (short)h; vl0[i] = (short)l;
        }
#pragma unroll
        for (int i = 0; i < 8; i++) {
            unsigned short h, l;
            split_bf16(Xs[(cc * 16 + 8 + i) * 65 + n], h, l);
            vh1[i] = (short)h; vl1[i] = (short)l;
        }
        const size_t off = ((size_t)b * N_TOK + n0 + n) * C_DIM + c0 + cc * 16;
        *(short8*)&Xhi[off] = vh0; *(short8*)&Xhi[off + 8] = vh1;
        *(short8*)&Xlo[off] = vl0; *(short8*)&Xlo[off + 8] = vl1;
    }
}

// ---------------------------------------------------------------------------
// proj_kernel: Out[n,o] = sum_c x[n,c]*W[o,c] + bias (+pos for K').
// (unchanged)
// ---------------------------------------------------------------------------
__global__ __launch_bounds__(256) void proj_kernel(
    const unsigned short* __restrict__ Xhi, const unsigned short* __restrict__ Xlo,
    const unsigned short* __restrict__ Whi, const unsigned short* __restrict__ Wlo,
    const float* __restrict__ bq, const float* __restrict__ bk, const float* __restrict__ bv,
    const float* __restrict__ relh, const float* __restrict__ relw,
    unsigned short* __restrict__ Qh,
    unsigned short* __restrict__ Kh,
    unsigned short* __restrict__ Vh)
{
    __shared__ unsigned short SM[20480];   // 40KB carve
    unsigned short* Ah = SM;               // [64][32]
    unsigned short* Al = SM + 2048;
    unsigned short* Bh = SM + 4096;        // [256][32]
    unsigned short* Bl = SM + 12288;

    const int t    = threadIdx.x;
    const int wave = t >> 6;
    const int lane = t & 63;
    const int l15  = lane & 15;
    const int quad = lane >> 4;

    const int bp   = blockIdx.x >> 6;
    const int proj = bp % 3;
    const int b    = bp / 3;
    const int n0   = (blockIdx.x & 63) * 64;

    const unsigned short* Xh = Xhi + ((size_t)b * N_TOK + n0) * C_DIM;
    const unsigned short* Xl = Xlo + ((size_t)b * N_TOK + n0) * C_DIM;
    const unsigned short* Wh = Whi + proj * 65536;
    const unsigned short* Wl = Wlo + proj * 65536;
    const float* bias = (proj == 0) ? bq : (proj == 1) ? bk : bv;
    const bool needlo = (proj < 2);

    floatx4 acc[16];
#pragma unroll
    for (int i = 0; i < 16; i++) acc[i] = (floatx4){0.f, 0.f, 0.f, 0.f};

    for (int c0 = 0; c0 < 256; c0 += 32) {
        {
            const int lr = lane >> 2, cp = lane & 3;
            const int key = (lr ^ (lr >> 2)) & 3;
            const int r = wave * 16 + lr;
            g2l16(Xh + (size_t)r * C_DIM + c0 + (cp ^ key) * 8, &Ah[wave * 512]);
            if (needlo) g2l16(Xl + (size_t)r * C_DIM + c0 + (cp ^ key) * 8, &Al[wave * 512]);
#pragma unroll
            for (int p = 0; p < 4; p++) {
                const int rb = (p * 4 + wave) * 16;
                const int rr = rb + lr;
                g2l16(Wh + (size_t)rr * 256 + c0 + (cp ^ key) * 8, &Bh[rb * 32]);
                if (needlo) g2l16(Wl + (size_t)rr * 256 + c0 + (cp ^ key) * 8, &Bl[rb * 32]);
            }
        }
        __syncthreads();

        const int akey = (l15 ^ (l15 >> 2)) & 3;
        const int arow = (wave * 16 + l15) * 32 + ((quad ^ akey) * 8);
        const short8 a_h = *(const short8*)&Ah[arow];
        short8 a_l;
        if (needlo) a_l = *(const short8*)&Al[arow];
#pragma unroll
        for (int ot = 0; ot < 16; ot++) {
            const int brow = (ot * 16 + l15) * 32 + ((quad ^ akey) * 8);
            const short8 b_h = *(const short8*)&Bh[brow];
            acc[ot] = __builtin_amdgcn_mfma_f32_16x16x32_bf16(a_h, b_h, acc[ot], 0, 0, 0);
            if (needlo) {
                const short8 b_l = *(const short8*)&Bl[brow];
                acc[ot] = __builtin_amdgcn_mfma_f32_16x16x32_bf16(a_l, b_h, acc[ot], 0, 0, 0);
                acc[ot] = __builtin_amdgcn_mfma_f32_16x16x32_bf16(a_h, b_l, acc[ot], 0, 0, 0);
            }
        }
        __syncthreads();
    }

    // ---- epilogue (all fp16 outputs) ----
    const int h0 = n0 >> 6;   // pos[c][n] = relh[c][n>>6] + relw[c][n&63]
    if (proj == 0) {
        unsigned short* Og = Qh + ((size_t)b * N_TOK + n0) * C_DIM;
#pragma unroll
        for (int ot = 0; ot < 16; ot++) {
            const int o = ot * 16 + l15;
            const float bs = bias[o];
#pragma unroll
            for (int r = 0; r < 4; r++) {
                const int nl = wave * 16 + quad * 4 + r;
                Og[(size_t)nl * C_DIM + o] = f2h(acc[ot][r] + bs);
            }
        }
    } else if (proj == 1) {
        unsigned short* Og = Kh + ((size_t)b * N_TOK + n0) * C_DIM;
#pragma unroll
        for (int ot = 0; ot < 16; ot++) {
            const int o = ot * 16 + l15;
            const float bs = bias[o];
            const float ph = relh[o * 64 + h0];
#pragma unroll
            for (int r = 0; r < 4; r++) {
                const int nl = wave * 16 + quad * 4 + r;
                Og[(size_t)nl * C_DIM + o] = f2h(acc[ot][r] + bs + ph + relw[o * 64 + nl]);
            }
        }
    } else {
        // V: fp16, transpose via LDS (reuse SM: 256x72 shorts = 36KB)
        unsigned short* Vt = SM;
#pragma unroll
        for (int ot = 0; ot < 16; ot++) {
            const int o = ot * 16 + l15;
            const float bs = bias[o];
            const unsigned int u0 = (unsigned int)f2h(acc[ot][0] + bs) |
                                    ((unsigned int)f2h(acc[ot][1] + bs) << 16);
            const unsigned int u1 = (unsigned int)f2h(acc[ot][2] + bs) |
                                    ((unsigned int)f2h(acc[ot][3] + bs) << 16);
            uint2 uv; uv.x = u0; uv.y = u1;
            *(uint2*)&Vt[o * 72 + wave * 16 + quad * 4] = uv;
        }
        __syncthreads();
        const int ch   = t & 7;
        const int orow = t >> 3;
#pragma unroll
        for (int pass = 0; pass < 8; pass++) {
            const int o = pass * 32 + orow;
            const short8 vv = *(const short8*)&Vt[o * 72 + ch * 8];
            *(short8*)&Vh[((size_t)b * C_DIM + o) * N_TOK + n0 + ch * 8] = vv;
        }
    }
}

// ---------------------------------------------------------------------------
// flash_kernel v3: swapped-S (S^T = mfma(K,Q)) so each lane owns the full
// 64-j row slice of one q (col = l15):
//   - softmax reduction = 2 shfl_xor (16,32) instead of 4; 1 alpha-exp/lane
//   - P^T -> PV B-fragment built ENTIRELY in registers (pack + quad
//     butterfly); Pt/abuf LDS deleted -> bank conflicts ~0, no per-iter
//     LDS round-trip. LDS = 64KB (Ks 32K + Vs 32K).
//   - l-sum kept per-lane partial; reduced once in epilogue.
//   - setprio(1) around both MFMA clusters (T5).
// Template: WPB = waves/block (8 -> 512thr, q-tile 128, NSPLIT=4, 16 iters;
//           4 -> 256thr, q-tile 64, NSPLIT=2, 32 iters  [ws fallback]).
// ---------------------------------------------------------------------------
template<int WPB, int NITER>
__global__ __launch_bounds__(WPB * 64, WPB / 2) void flash_kernel(
    const unsigned short* __restrict__ Qg,   // fp16 [4][4096][256]
    const unsigned short* __restrict__ Kg,   // fp16 [4][4096][256] (k+pos)
    const unsigned short* __restrict__ Vg,   // fp16 [4][256][4096]
    unsigned short* __restrict__ Op,         // fp16 [NS][4][256][4096]
    float* __restrict__ Lm)                  // [NS][4][4096] float2 (m,l)
{
    static_assert(WPB == 4 || WPB == 8, "WPB");
    constexpr int NS    = N_TOK / (NITER * 64);
    constexpr int QTILE = WPB * 16;
    constexpr int QSH   = (NS == 4) ? 4 : 3;

    __shared__ unsigned short Ks[64 * 256];   // 32KB  K' tile [j][c]
    __shared__ unsigned short Vs[256 * 64];   // 32KB  V tile [c][j]

    const int t    = threadIdx.x;
    const int wave = t >> 6;
    const int lane = t & 63;
    const int l15  = lane & 15;
    const int quad = lane >> 4;
    const int lk   = l15 & 7;   // LDS chunk-swizzle key

    const int bid = blockIdx.x;
    const int b   = bid & 3;
    const int s   = (bid >> 2) & (NS - 1);
    const int qt  = bid >> QSH;

    const unsigned short* Kb = Kg + (size_t)b * N_TOK * C_DIM;
    const unsigned short* Vb = Vg + (size_t)b * C_DIM * N_TOK;

    // Q fragments resident in registers: 16 rows x 256c per wave
    half8 qf[8];
    const int qrow = qt * QTILE + wave * 16 + l15;
    {
        const unsigned short* Qrow = Qg + ((size_t)b * N_TOK + qrow) * C_DIM;
#pragma unroll
        for (int ct = 0; ct < 8; ct++)
            qf[ct] = *(const half8*)&Qrow[ct * 32 + quad * 8];
    }

    floatx4 oacc[16];
#pragma unroll
    for (int i = 0; i < 16; i++) oacc[i] = (floatx4){0.f, 0.f, 0.f, 0.f};
    float m_i = -1e30f;     // per-lane (q = l15 col)
    float l_i = 0.f;        // per-lane PARTIAL (this quad's 16 j's)

    const int jbase = s * (NITER * 64);
    const int oddq  = quad & 1;
    const int hiq   = quad >> 1;
    const int own   = (quad == 0) | (quad == 3);

    // ---- preamble: stage K tile 0
    {
        const int lr = lane >> 5, cp = lane & 31;
#pragma unroll
        for (int p = 0; p < 64 / WPB / 2; p++) {
            const int jl = wave * (64 / WPB) + p * 2 + lr;
            g2l16(Kb + (size_t)(jbase + jl) * C_DIM + (cp ^ (jl & 7)) * 8,
                  &Ks[(wave * (64 / WPB) + p * 2) * 256]);
        }
    }

    for (int ti = 0; ti < NITER; ti++) {
        const int j0 = jbase + ti * 64;

        __syncthreads();   // B1: K(ti) visible; PV(ti-1) V-reads done

        // ---- stage V(ti) async (flies under S-MFMAs)
        {
            const int lr = lane >> 3, cp = lane & 7;
#pragma unroll
            for (int p = 0; p < 32 / WPB; p++) {
                const int ob = (p * WPB + wave) * 8;
                const int o  = ob + lr;
                g2l16(Vb + (size_t)o * N_TOK + j0 + (cp ^ (o & 7)) * 8, &Vs[ob * 64]);
            }
        }

        // ---- S^T = K' Q^T : sv[jt][r] = S^T[j = 16jt+4quad+r][q = l15]
        floatx4 sv[4];
        __builtin_amdgcn_s_setprio(1);
#pragma unroll
        for (int jt = 0; jt < 4; jt++) {
            floatx4 a = (floatx4){0.f, 0.f, 0.f, 0.f};
#pragma unroll
            for (int ct = 0; ct < 8; ct++) {
                const half8 kb = *(const half8*)&Ks[(jt * 16 + l15) * 256 + (((ct * 4 + quad) ^ lk) * 8)];
                a = __builtin_amdgcn_mfma_f32_16x16x32_f16(kb, qf[ct], a, 0, 0, 0);
            }
            sv[jt] = a;
        }
        __builtin_amdgcn_s_setprio(0);

        // ---- per-lane online softmax (16 j-values/lane; reduce over 4 quads)
        float mx;
        {
            const float a0 = fmaxf(fmaxf(sv[0][0], sv[0][1]), fmaxf(sv[0][2], sv[0][3]));
            const float a1 = fmaxf(fmaxf(sv[1][0], sv[1][1]), fmaxf(sv[1][2], sv[1][3]));
            const float a2 = fmaxf(fmaxf(sv[2][0], sv[2][1]), fmaxf(sv[2][2], sv[2][3]));
            const float a3 = fmaxf(fmaxf(sv[3][0], sv[3][1]), fmaxf(sv[3][2], sv[3][3]));
            mx = fmaxf(fmaxf(a0, a1), fmaxf(a2, a3));
        }
        mx = fmaxf(mx, __shfl_xor(mx, 16));
        mx = fmaxf(mx, __shfl_xor(mx, 32));
        const float mn    = fmaxf(m_i, mx);
        const float alpha = __expf(m_i - mn);
        m_i = mn;
        float ps = 0.f;
#pragma unroll
        for (int jt = 0; jt < 4; jt++) {
#pragma unroll
            for (int r = 0; r < 4; r++) {
                const float p = __expf(sv[jt][r] - mn);
                sv[jt][r] = p;
                ps += p;
            }
        }
        l_i = l_i * alpha + ps;   // partial: cross-quad reduce in epilogue

        // ---- P^T -> PV B-fragments entirely in registers.
        // Target lane (quad',l15): pfX word w = half2 of j-pair
        // (32X + 8quad' + 2w, +1), col l15.  Source word U[jt][h] (lane q)
        // holds j-pair (16jt + 4q + 2h, +1).  Route: shfl_xor16 (pair
        // exchange) -> jt-select -> shfl_xor32 -> own/other select.
        half8 pf0, pf1;
        {   // batch 0: jt {0,1} -> pf0
            const unsigned int u00 = pack2h(sv[0][0], sv[0][1]);
            const unsigned int u01 = pack2h(sv[0][2], sv[0][3]);
            const unsigned int u10 = pack2h(sv[1][0], sv[1][1]);
            const unsigned int u11 = pack2h(sv[1][2], sv[1][3]);
            const unsigned int t00 = __shfl_xor(u00, 16), t01 = __shfl_xor(u01, 16);
            const unsigned int t10 = __shfl_xor(u10, 16), t11 = __shfl_xor(u11, 16);
            const unsigned int L00 = oddq ? t00 : u00, H00 = oddq ? u00 : t00;
            const unsigned int L01 = oddq ? t01 : u01, H01 = oddq ? u01 : t01;
            const unsigned int L10 = oddq ? t10 : u10, H10 = oddq ? u10 : t10;
            const unsigned int L11 = oddq ? t11 : u11, H11 = oddq ? u11 : t11;
            const unsigned int ke0 = hiq ? L10 : L00, se0 = hiq ? L00 : L10;
            const unsigned int ke1 = hiq ? L11 : L01, se1 = hiq ? L01 : L11;
            const unsigned int ko0 = hiq ? H10 : H00, so0 = hiq ? H00 : H10;
            const unsigned int ko1 = hiq ? H11 : H01, so1 = hiq ? H01 : H11;
            const unsigned int re0 = __shfl_xor(se0, 32), re1 = __shfl_xor(se1, 32);
            const unsigned int ro0 = __shfl_xor(so0, 32), ro1 = __shfl_xor(so1, 32);
            union { unsigned int u[4]; half8 h; } pk;
            pk.u[0] = own ? ke0 : re0;
            pk.u[1] = own ? ke1 : re1;
            pk.u[2] = own ? ko0 : ro0;
            pk.u[3] = own ? ko1 : ro1;
            pf0 = pk.h;
        }
        {   // batch 1: jt {2,3} -> pf1
            const unsigned int u00 = pack2h(sv[2][0], sv[2][1]);
            const unsigned int u01 = pack2h(sv[2][2], sv[2][3]);
            const unsigned int u10 = pack2h(sv[3][0], sv[3][1]);
            const unsigned int u11 = pack2h(sv[3][2], sv[3][3]);
            const unsigned int t00 = __shfl_xor(u00, 16), t01 = __shfl_xor(u01, 16);
            const unsigned int t10 = __shfl_xor(u10, 16), t11 = __shfl_xor(u11, 16);
            const unsigned int L00 = oddq ? t00 : u00, H00 = oddq ? u00 : t00;
            const unsigned int L01 = oddq ? t01 : u01, H01 = oddq ? u01 : t01;
            const unsigned int L10 = oddq ? t10 : u10, H10 = oddq ? u10 : t10;
            const unsigned int L11 = oddq ? t11 : u11, H11 = oddq ? u11 : t11;
            const unsigned int ke0 = hiq ? L10 : L00, se0 = hiq ? L00 : L10;
            const unsigned int ke1 = hiq ? L11 : L01, se1 = hiq ? L01 : L11;
            const unsigned int ko0 = hiq ? H10 : H00, so0 = hiq ? H00 : H10;
            const unsigned int ko1 = hiq ? H11 : H01, so1 = hiq ? H01 : H11;
            const unsigned int re0 = __shfl_xor(se0, 32), re1 = __shfl_xor(se1, 32);
            const unsigned int ro0 = __shfl_xor(so0, 32), ro1 = __shfl_xor(so1, 32);
            union { unsigned int u[4]; half8 h; } pk;
            pk.u[0] = own ? ke0 : re0;
            pk.u[1] = own ? ke1 : re1;
            pk.u[2] = own ? ko0 : ro0;
            pk.u[3] = own ? ko1 : ro1;
            pf1 = pk.h;
        }

        // ---- rescale O (alpha is per-lane scalar: col q = l15)
#pragma unroll
        for (int ot = 0; ot < 16; ot++) {
            oacc[ot][0] *= alpha; oacc[ot][1] *= alpha;
            oacc[ot][2] *= alpha; oacc[ot][3] *= alpha;
        }

        __syncthreads();   // B2: V(ti) visible; all waves done reading K(ti)

        // ---- stage K(ti+1) async (flies under PV-MFMAs)
        if (ti < NITER - 1) {
            const int lr = lane >> 5, cp = lane & 31;
#pragma unroll
            for (int p = 0; p < 64 / WPB / 2; p++) {
                const int jl = wave * (64 / WPB) + p * 2 + lr;
                g2l16(Kb + (size_t)(j0 + 64 + jl) * C_DIM + (cp ^ (jl & 7)) * 8,
                      &Ks[(wave * (64 / WPB) + p * 2) * 256]);
            }
        }

        // ---- O^T += V P^T
        __builtin_amdgcn_s_setprio(1);
#pragma unroll
        for (int ot = 0; ot < 16; ot++) {
            const int row = (ot * 16 + l15) * 64;
            const half8 av0 = *(const half8*)&Vs[row + ((quad ^ lk) * 8)];
            const half8 av1 = *(const half8*)&Vs[row + (((4 + quad) ^ lk) * 8)];
            oacc[ot] = __builtin_amdgcn_mfma_f32_16x16x32_f16(av0, pf0, oacc[ot], 0, 0, 0);
            oacc[ot] = __builtin_amdgcn_mfma_f32_16x16x32_f16(av1, pf1, oacc[ot], 0, 0, 0);
        }
        __builtin_amdgcn_s_setprio(0);
    }

    // ---- epilogue: unnormalized O^T fp16 + (m,l)
    unsigned short* Ob = Op + ((size_t)(s * 4 + b) * C_DIM) * N_TOK;
    const int n = qt * QTILE + wave * 16 + l15;
#pragma unroll
    for (int ot = 0; ot < 16; ot++) {
#pragma unroll
        for (int r = 0; r < 4; r++) {
            const int c = ot * 16 + quad * 4 + r;
            Ob[(size_t)c * N_TOK + n] = f2h(oacc[ot][r]);
        }
    }
    float lt = l_i;
    lt += __shfl_xor(lt, 16);
    lt += __shfl_xor(lt, 32);
    if (quad == 0) {
        const size_t nb = (size_t)(s * 4 + b) * N_TOK + n;
        *(float2*)&Lm[nb * 2] = make_float2(m_i, lt);
    }
}

// ---------------------------------------------------------------------------
// merge_kernel: out = gamma * (sum_s w_s O_s) / (sum_s w_s l_s) + x
// ---------------------------------------------------------------------------
template<int NS>
__global__ __launch_bounds__(256) void merge_kernel(
    const unsigned short* __restrict__ Op,
    const float* __restrict__ Lm,
    const float* __restrict__ x,
    const float* __restrict__ gamma,
    float* __restrict__ out)
{
    const int blk = blockIdx.x;          // 4096
    const int b   = blk >> 10;
    const int c   = (blk >> 2) & 255;
    const int nq  = blk & 3;
    const int n0  = nq * 1024 + threadIdx.x * 4;

    const size_t NEo = (size_t)4 * C_DIM * N_TOK;
    const size_t obase = ((size_t)b * C_DIM + c) * N_TOK + n0;

    float ms[NS][4], ls[NS][4], os[NS][4];
#pragma unroll
    for (int s = 0; s < NS; s++) {
        const uint2 u = *(const uint2*)&Op[s * NEo + obase];
        os[s][0] = h2f((unsigned short)(u.x & 0xffff));
        os[s][1] = h2f((unsigned short)(u.x >> 16));
        os[s][2] = h2f((unsigned short)(u.y & 0xffff));
        os[s][3] = h2f((unsigned short)(u.y >> 16));
        const float* Lms = Lm + (size_t)(s * 4 + b) * N_TOK * 2;
        const float4 A0 = *(const float4*)&Lms[n0 * 2];
        const float4 A1 = *(const float4*)&Lms[n0 * 2 + 4];
        ms[s][0] = A0.x; ls[s][0] = A0.y;
        ms[s][1] = A0.z; ls[s][1] = A0.w;
        ms[s][2] = A1.x; ls[s][2] = A1.y;
        ms[s][3] = A1.z; ls[s][3] = A1.w;
    }
    const float4 xv = *(const float4*)&x[obase];
    const float xin[4] = {xv.x, xv.y, xv.z, xv.w};
    const float g = gamma[0];

    float4 res;
    float* rp = (float*)&res;
#pragma unroll
    for (int i = 0; i < 4; i++) {
        float M = ms[0][i];
#pragma unroll
        for (int s = 1; s < NS; s++) M = fmaxf(M, ms[s][i]);
        float osum = 0.f, lsum = 0.f;
#pragma unroll
        for (int s = 0; s < NS; s++) {
            const float w = __expf(ms[s][i] - M);
            osum += w * os[s][i];
            lsum += w * ls[s][i];
        }
        rp[i] = g * osum / lsum + xin[i];
    }
    *(float4*)&out[obase] = res;
}

extern "C" void kernel_launch(void* const* d_in, const int* in_sizes, int n_in,
                              void* d_out, int out_size, void* d_ws, size_t ws_size,
                              hipStream_t stream) {
    const float* x     = (const float*)d_in[0];
    const float* Wq    = (const float*)d_in[1];
    const float* bq    = (const float*)d_in[2];
    const float* Wk    = (const float*)d_in[3];
    const float* bk    = (const float*)d_in[4];
    const float* Wv    = (const float*)d_in[5];
    const float* bv    = (const float*)d_in[6];
    const float* relh  = (const float*)d_in[7];
    const float* relw  = (const float*)d_in[8];
    const float* gamma = (const float*)d_in[9];
    float* out = (float*)d_out;

    const size_t NE = (size_t)4 * N_TOK * C_DIM;   // 4.19M elems

    // NS=4 needs: Op 4NE u16 + W 6*65536 u16 + QKV 3NE u16 + Lm 4*4*4096*2 f32
    const size_t need4 = ((size_t)7 * NE + 6 * 65536) * 2 + (size_t)4 * 4 * N_TOK * 2 * 4;
    const int NS = (ws_size >= need4) ? 4 : 2;

    // Region layout (Op overlays Xhi/Xlo: X dead before flash writes Op)
    unsigned short* Op  = (unsigned short*)d_ws;           // NS*NE u16
    unsigned short* Xhi = Op;                              // NE u16 (prep/proj only)
    unsigned short* Xlo = Op + NE;                         // NE u16
    unsigned short* Whi = Op + (size_t)NS * NE;            // 3*65536 u16
    unsigned short* Wlo = Whi + 3 * 65536;
    unsigned short* Qh  = Wlo + 3 * 65536;                 // NE u16 (fp16)
    unsigned short* Kh  = Qh + NE;                         // NE u16 (fp16)
    unsigned short* Vh  = Kh + NE;                         // NE u16 (fp16)
    float* Lm = (float*)(Vh + NE);                         // NS*4*4096*2 floats

    hipLaunchKernelGGL(prep_kernel, dim3(1027), dim3(256), 0, stream,
                       x, Wq, Wk, Wv, Xhi, Xlo, Whi, Wlo);
    hipLaunchKernelGGL(proj_kernel, dim3(768), dim3(256), 0, stream,
                       Xhi, Xlo, Whi, Wlo, bq, bk, bv, relh, relw, Qh, Kh, Vh);
    if (NS == 4) {
        hipLaunchKernelGGL((flash_kernel<8, 16>), dim3(512), dim3(512), 0, stream,
                           Qh, Kh, Vh, Op, Lm);
        hipLaunchKernelGGL((merge_kernel<4>), dim3(4096), dim3(256), 0, stream,
                           Op, Lm, x, gamma, out);
    } else {
        hipLaunchKernelGGL((flash_kernel<4, 32>), dim3(512), dim3(256), 0, stream,
                           Qh, Kh, Vh, Op, Lm);
        hipLaunchKernelGGL((merge_kernel<2>), dim3(4096), dim3(256), 0, stream,
                           Op, Lm, x, gamma, out);
    }
}

// Round 2
// 249.592 us; speedup vs baseline: 1.6090x; 1.6090x over previous
//
#include <hip/hip_runtime.h>
#include <stdint.h>

#define N_TOK 4096
#define C_DIM 256

typedef __attribute__((ext_vector_type(8))) short short8;
typedef __attribute__((ext_vector_type(8))) _Float16 half8;
typedef __attribute__((ext_vector_type(4))) float floatx4;
typedef __attribute__((ext_vector_type(4))) unsigned short ushort4v;

__device__ __forceinline__ unsigned short bf16_rne(float f) {
    union { float f; unsigned int u; } v; v.f = f;
    unsigned int u = v.u;
    unsigned int rounded = u + 0x7FFFu + ((u >> 16) & 1u);
    return (unsigned short)(rounded >> 16);
}
__device__ __forceinline__ float bf16_to_f(unsigned short h) {
    union { unsigned int u; float f; } v; v.u = ((unsigned int)h) << 16;
    return v.f;
}
__device__ __forceinline__ void split_bf16(float f, unsigned short& h, unsigned short& l) {
    h = bf16_rne(f);
    l = bf16_rne(f - bf16_to_f(h));
}
__device__ __forceinline__ unsigned short f2h(float f) {
    union { _Float16 h; unsigned short u; } v; v.h = (_Float16)f; return v.u;
}
__device__ __forceinline__ float h2f(unsigned short u) {
    union { unsigned short u; _Float16 h; } v; v.u = u; return (float)v.h;
}
// pack two floats -> half2 (RNE)
__device__ __forceinline__ unsigned int pack2h(float a, float b) {
    union { _Float16 h[2]; unsigned int u; } v;
    v.h[0] = (_Float16)a; v.h[1] = (_Float16)b;
    return v.u;
}
// async global->LDS 16B/lane; LDS dest = wave-uniform base + lane*16
__device__ __forceinline__ void g2l16(const void* g, void* l) {
    __builtin_amdgcn_global_load_lds(
        (const __attribute__((address_space(1))) void*)g,
        (__attribute__((address_space(3))) void*)l, 16, 0, 0);
}

// ---------------------------------------------------------------------------
// prep_kernel: one-time split/transpose (bf16 hi/lo pairs for fp32-accurate
// projection GEMM).  (unchanged)
// ---------------------------------------------------------------------------
__global__ __launch_bounds__(256) void prep_kernel(
    const float* __restrict__ x,
    const float* __restrict__ Wq, const float* __restrict__ Wk, const float* __restrict__ Wv,
    unsigned short* __restrict__ Xhi, unsigned short* __restrict__ Xlo,
    unsigned short* __restrict__ Whi, unsigned short* __restrict__ Wlo)
{
    const int t = threadIdx.x;
    if (blockIdx.x >= 1024) {
        const int pj = blockIdx.x - 1024;
        const float* W = (pj == 0) ? Wq : (pj == 1) ? Wk : Wv;
        unsigned short* dh = Whi + pj * 65536;
        unsigned short* dl = Wlo + pj * 65536;
        for (int it = 0; it < 64; it++) {
            const int idx = it * 1024 + t * 4;
            const float4 w = *(const float4*)&W[idx];
            unsigned short h0, l0, h1, l1, h2, l2, h3, l3;
            split_bf16(w.x, h0, l0); split_bf16(w.y, h1, l1);
            split_bf16(w.z, h2, l2); split_bf16(w.w, h3, l3);
            ushort4v vh; vh[0] = h0; vh[1] = h1; vh[2] = h2; vh[3] = h3;
            ushort4v vl; vl[0] = l0; vl[1] = l1; vl[2] = l2; vl[3] = l3;
            *(ushort4v*)&dh[idx] = vh;
            *(ushort4v*)&dl[idx] = vl;
        }
        return;
    }
    __shared__ float Xs[64 * 65];   // pitch 65: conflict-free transpose
    const int b  = blockIdx.x >> 8;
    const int ct = (blockIdx.x >> 6) & 3;
    const int nt = blockIdx.x & 63;
    const int c0 = ct * 64, n0 = nt * 64;
    {
        const int nch = t & 15, cr = t >> 4;
#pragma unroll
        for (int pass = 0; pass < 4; pass++) {
            const int c = pass * 16 + cr;
            const float4 v = *(const float4*)&x[((size_t)(b * C_DIM + c0 + c)) * N_TOK + n0 + nch * 4];
            float* row = &Xs[c * 65 + nch * 4];
            row[0] = v.x; row[1] = v.y; row[2] = v.z; row[3] = v.w;
        }
    }
    __syncthreads();
    {
        const int n = t >> 2, cc = t & 3;
        short8 vh0, vl0, vh1, vl1;
#pragma unroll
        for (int i = 0; i < 8; i++) {
            unsigned short h, l;
            split_bf16(Xs[(cc * 16 + i) * 65 + n], h, l);
            vh0[i] = (short)h; vl0[i] = (short)l;
        }
#pragma unroll
        for (int i = 0; i < 8; i++) {
            unsigned short h, l;
            split_bf16(Xs[(cc * 16 + 8 + i) * 65 + n], h, l);
            vh1[i] = (short)h; vl1[i] = (short)l;
        }
        const size_t off = ((size_t)b * N_TOK + n0 + n) * C_DIM + c0 + cc * 16;
        *(short8*)&Xhi[off] = vh0; *(short8*)&Xhi[off + 8] = vh1;
        *(short8*)&Xlo[off] = vl0; *(short8*)&Xlo[off + 8] = vl1;
    }
}

// ---------------------------------------------------------------------------
// proj_kernel: Out[n,o] = sum_c x[n,c]*W[o,c] + bias (+pos for K').
// (unchanged)
// ---------------------------------------------------------------------------
__global__ __launch_bounds__(256) void proj_kernel(
    const unsigned short* __restrict__ Xhi, const unsigned short* __restrict__ Xlo,
    const unsigned short* __restrict__ Whi, const unsigned short* __restrict__ Wlo,
    const float* __restrict__ bq, const float* __restrict__ bk, const float* __restrict__ bv,
    const float* __restrict__ relh, const float* __restrict__ relw,
    unsigned short* __restrict__ Qh,
    unsigned short* __restrict__ Kh,
    unsigned short* __restrict__ Vh)
{
    __shared__ unsigned short SM[20480];   // 40KB carve
    unsigned short* Ah = SM;               // [64][32]
    unsigned short* Al = SM + 2048;
    unsigned short* Bh = SM + 4096;        // [256][32]
    unsigned short* Bl = SM + 12288;

    const int t    = threadIdx.x;
    const int wave = t >> 6;
    const int lane = t & 63;
    const int l15  = lane & 15;
    const int quad = lane >> 4;

    const int bp   = blockIdx.x >> 6;
    const int proj = bp % 3;
    const int b    = bp / 3;
    const int n0   = (blockIdx.x & 63) * 64;

    const unsigned short* Xh = Xhi + ((size_t)b * N_TOK + n0) * C_DIM;
    const unsigned short* Xl = Xlo + ((size_t)b * N_TOK + n0) * C_DIM;
    const unsigned short* Wh = Whi + proj * 65536;
    const unsigned short* Wl = Wlo + proj * 65536;
    const float* bias = (proj == 0) ? bq : (proj == 1) ? bk : bv;
    const bool needlo = (proj < 2);

    floatx4 acc[16];
#pragma unroll
    for (int i = 0; i < 16; i++) acc[i] = (floatx4){0.f, 0.f, 0.f, 0.f};

    for (int c0 = 0; c0 < 256; c0 += 32) {
        {
            const int lr = lane >> 2, cp = lane & 3;
            const int key = (lr ^ (lr >> 2)) & 3;
            const int r = wave * 16 + lr;
            g2l16(Xh + (size_t)r * C_DIM + c0 + (cp ^ key) * 8, &Ah[wave * 512]);
            if (needlo) g2l16(Xl + (size_t)r * C_DIM + c0 + (cp ^ key) * 8, &Al[wave * 512]);
#pragma unroll
            for (int p = 0; p < 4; p++) {
                const int rb = (p * 4 + wave) * 16;
                const int rr = rb + lr;
                g2l16(Wh + (size_t)rr * 256 + c0 + (cp ^ key) * 8, &Bh[rb * 32]);
                if (needlo) g2l16(Wl + (size_t)rr * 256 + c0 + (cp ^ key) * 8, &Bl[rb * 32]);
            }
        }
        __syncthreads();

        const int akey = (l15 ^ (l15 >> 2)) & 3;
        const int arow = (wave * 16 + l15) * 32 + ((quad ^ akey) * 8);
        const short8 a_h = *(const short8*)&Ah[arow];
        short8 a_l;
        if (needlo) a_l = *(const short8*)&Al[arow];
#pragma unroll
        for (int ot = 0; ot < 16; ot++) {
            const int brow = (ot * 16 + l15) * 32 + ((quad ^ akey) * 8);
            const short8 b_h = *(const short8*)&Bh[brow];
            acc[ot] = __builtin_amdgcn_mfma_f32_16x16x32_bf16(a_h, b_h, acc[ot], 0, 0, 0);
            if (needlo) {
                const short8 b_l = *(const short8*)&Bl[brow];
                acc[ot] = __builtin_amdgcn_mfma_f32_16x16x32_bf16(a_l, b_h, acc[ot], 0, 0, 0);
                acc[ot] = __builtin_amdgcn_mfma_f32_16x16x32_bf16(a_h, b_l, acc[ot], 0, 0, 0);
            }
        }
        __syncthreads();
    }

    // ---- epilogue (all fp16 outputs) ----
    const int h0 = n0 >> 6;   // pos[c][n] = relh[c][n>>6] + relw[c][n&63]
    if (proj == 0) {
        unsigned short* Og = Qh + ((size_t)b * N_TOK + n0) * C_DIM;
#pragma unroll
        for (int ot = 0; ot < 16; ot++) {
            const int o = ot * 16 + l15;
            const float bs = bias[o];
#pragma unroll
            for (int r = 0; r < 4; r++) {
                const int nl = wave * 16 + quad * 4 + r;
                Og[(size_t)nl * C_DIM + o] = f2h(acc[ot][r] + bs);
            }
        }
    } else if (proj == 1) {
        unsigned short* Og = Kh + ((size_t)b * N_TOK + n0) * C_DIM;
#pragma unroll
        for (int ot = 0; ot < 16; ot++) {
            const int o = ot * 16 + l15;
            const float bs = bias[o];
            const float ph = relh[o * 64 + h0];
#pragma unroll
            for (int r = 0; r < 4; r++) {
                const int nl = wave * 16 + quad * 4 + r;
                Og[(size_t)nl * C_DIM + o] = f2h(acc[ot][r] + bs + ph + relw[o * 64 + nl]);
            }
        }
    } else {
        // V: fp16, transpose via LDS (reuse SM: 256x72 shorts = 36KB)
        unsigned short* Vt = SM;
#pragma unroll
        for (int ot = 0; ot < 16; ot++) {
            const int o = ot * 16 + l15;
            const float bs = bias[o];
            const unsigned int u0 = (unsigned int)f2h(acc[ot][0] + bs) |
                                    ((unsigned int)f2h(acc[ot][1] + bs) << 16);
            const unsigned int u1 = (unsigned int)f2h(acc[ot][2] + bs) |
                                    ((unsigned int)f2h(acc[ot][3] + bs) << 16);
            uint2 uv; uv.x = u0; uv.y = u1;
            *(uint2*)&Vt[o * 72 + wave * 16 + quad * 4] = uv;
        }
        __syncthreads();
        const int ch   = t & 7;
        const int orow = t >> 3;
#pragma unroll
        for (int pass = 0; pass < 8; pass++) {
            const int o = pass * 32 + orow;
            const short8 vv = *(const short8*)&Vt[o * 72 + ch * 8];
            *(short8*)&Vh[((size_t)b * C_DIM + o) * N_TOK + n0 + ch * 8] = vv;
        }
    }
}

// ---------------------------------------------------------------------------
// flash_kernel v4: swapped-S (S^T = mfma(K,Q)), register-only P butterfly,
// per-lane softmax state, T13 defer-max, setprio around MFMA clusters.
// Fixed config: 4 waves / 256 threads, NSPLIT=2, 32 iters, LDS 64KB.
// __launch_bounds__(256,2): both HIP interpretations give VGPR cap 256
// (the (512,4) variant of round 1 was read as 4 BLOCKS/CU -> 64-VGPR cap
//  -> total scratch spill; 256-thread blocks are immune to the ambiguity).
// ---------------------------------------------------------------------------
__global__ __launch_bounds__(256, 2) void flash_kernel(
    const unsigned short* __restrict__ Qg,   // fp16 [4][4096][256]
    const unsigned short* __restrict__ Kg,   // fp16 [4][4096][256] (k+pos)
    const unsigned short* __restrict__ Vg,   // fp16 [4][256][4096]
    unsigned short* __restrict__ Op,         // fp16 [2][4][256][4096]
    float* __restrict__ Lm)                  // [2][4][4096] float2 (m,l)
{
    constexpr int NITER = 32;

    __shared__ unsigned short Ks[64 * 256];   // 32KB  K' tile [j][c]
    __shared__ unsigned short Vs[256 * 64];   // 32KB  V tile [c][j]

    const int t    = threadIdx.x;
    const int wave = t >> 6;
    const int lane = t & 63;
    const int l15  = lane & 15;
    const int quad = lane >> 4;
    const int lk   = l15 & 7;   // LDS chunk-swizzle key

    const int bid = blockIdx.x;
    const int b   = bid & 3;
    const int s   = (bid >> 2) & 1;
    const int qt  = bid >> 3;         // 0..63

    const unsigned short* Kb = Kg + (size_t)b * N_TOK * C_DIM;
    const unsigned short* Vb = Vg + (size_t)b * C_DIM * N_TOK;

    // Q fragments resident in registers: 16 rows x 256c per wave
    half8 qf[8];
    const int qrow = qt * 64 + wave * 16 + l15;
    {
        const unsigned short* Qrow = Qg + ((size_t)b * N_TOK + qrow) * C_DIM;
#pragma unroll
        for (int ct = 0; ct < 8; ct++)
            qf[ct] = *(const half8*)&Qrow[ct * 32 + quad * 8];
    }

    floatx4 oacc[16];
#pragma unroll
    for (int i = 0; i < 16; i++) oacc[i] = (floatx4){0.f, 0.f, 0.f, 0.f};
    float m_i = -1e30f;     // per-lane running max (q = l15 col)
    float l_i = 0.f;        // per-lane PARTIAL sum (this quad's 16 j's)

    const int jbase = s * (NITER * 64);
    const int oddq  = quad & 1;
    const int hiq   = quad >> 1;
    const int own   = (quad == 0) | (quad == 3);

    // ---- preamble: stage K tile 0
    {
        const int lr = lane >> 5, cp = lane & 31;
#pragma unroll
        for (int p = 0; p < 8; p++) {
            const int jl = wave * 16 + p * 2 + lr;
            g2l16(Kb + (size_t)(jbase + jl) * C_DIM + (cp ^ (jl & 7)) * 8,
                  &Ks[(wave * 16 + p * 2) * 256]);
        }
    }

    for (int ti = 0; ti < NITER; ti++) {
        const int j0 = jbase + ti * 64;

        __syncthreads();   // B1: K(ti) visible; PV(ti-1) V-reads done

        // ---- stage V(ti) async (flies under S-MFMAs)
        {
            const int lr = lane >> 3, cp = lane & 7;
#pragma unroll
            for (int p = 0; p < 8; p++) {
                const int ob = (p * 4 + wave) * 8;
                const int o  = ob + lr;
                g2l16(Vb + (size_t)o * N_TOK + j0 + (cp ^ (o & 7)) * 8, &Vs[ob * 64]);
            }
        }

        // ---- S^T = K' Q^T : sv[jt][r] = S^T[j = 16jt+4quad+r][q = l15]
        floatx4 sv[4];
        __builtin_amdgcn_s_setprio(1);
#pragma unroll
        for (int jt = 0; jt < 4; jt++) {
            floatx4 a = (floatx4){0.f, 0.f, 0.f, 0.f};
#pragma unroll
            for (int ct = 0; ct < 8; ct++) {
                const half8 kb = *(const half8*)&Ks[(jt * 16 + l15) * 256 + (((ct * 4 + quad) ^ lk) * 8)];
                a = __builtin_amdgcn_mfma_f32_16x16x32_f16(kb, qf[ct], a, 0, 0, 0);
            }
            sv[jt] = a;
        }
        __builtin_amdgcn_s_setprio(0);

        // ---- per-lane online softmax (16 j-values/lane; reduce over 4 quads)
        float mx;
        {
            const float a0 = fmaxf(fmaxf(sv[0][0], sv[0][1]), fmaxf(sv[0][2], sv[0][3]));
            const float a1 = fmaxf(fmaxf(sv[1][0], sv[1][1]), fmaxf(sv[1][2], sv[1][3]));
            const float a2 = fmaxf(fmaxf(sv[2][0], sv[2][1]), fmaxf(sv[2][2], sv[2][3]));
            const float a3 = fmaxf(fmaxf(sv[3][0], sv[3][1]), fmaxf(sv[3][2], sv[3][3]));
            mx = fmaxf(fmaxf(a0, a1), fmaxf(a2, a3));
        }
        mx = fmaxf(mx, __shfl_xor(mx, 16));
        mx = fmaxf(mx, __shfl_xor(mx, 32));

        // T13 defer-max: skip alpha/rescale when tile max growth <= 8
        // (P bounded by e^8 ~ 2981, safe in fp16; accumulators fp32).
        if (!__all(mx <= m_i + 8.f)) {
            const float mn    = fmaxf(m_i, mx);
            const float alpha = __expf(m_i - mn);
            m_i = mn;
            l_i *= alpha;
#pragma unroll
            for (int ot = 0; ot < 16; ot++) {
                oacc[ot][0] *= alpha; oacc[ot][1] *= alpha;
                oacc[ot][2] *= alpha; oacc[ot][3] *= alpha;
            }
        }
        float ps = 0.f;
#pragma unroll
        for (int jt = 0; jt < 4; jt++) {
#pragma unroll
            for (int r = 0; r < 4; r++) {
                const float p = __expf(sv[jt][r] - m_i);
                sv[jt][r] = p;
                ps += p;
            }
        }
        l_i += ps;   // partial: cross-quad reduce in epilogue

        // ---- P^T -> PV B-fragments entirely in registers.
        // Target lane (quad',l15): pfX word w = half2 of j-pair
        // (32X + 8quad' + 2w, +1), col l15.  Source word U[jt][h] (lane q)
        // holds j-pair (16jt + 4q + 2h, +1).  Route: shfl_xor16 (pair
        // exchange) -> jt-select -> shfl_xor32 -> own/other select.
        half8 pf0, pf1;
        {   // batch 0: jt {0,1} -> pf0
            const unsigned int u00 = pack2h(sv[0][0], sv[0][1]);
            const unsigned int u01 = pack2h(sv[0][2], sv[0][3]);
            const unsigned int u10 = pack2h(sv[1][0], sv[1][1]);
            const unsigned int u11 = pack2h(sv[1][2], sv[1][3]);
            const unsigned int t00 = __shfl_xor(u00, 16), t01 = __shfl_xor(u01, 16);
            const unsigned int t10 = __shfl_xor(u10, 16), t11 = __shfl_xor(u11, 16);
            const unsigned int L00 = oddq ? t00 : u00, H00 = oddq ? u00 : t00;
            const unsigned int L01 = oddq ? t01 : u01, H01 = oddq ? u01 : t01;
            const unsigned int L10 = oddq ? t10 : u10, H10 = oddq ? u10 : t10;
            const unsigned int L11 = oddq ? t11 : u11, H11 = oddq ? u11 : t11;
            const unsigned int ke0 = hiq ? L10 : L00, se0 = hiq ? L00 : L10;
            const unsigned int ke1 = hiq ? L11 : L01, se1 = hiq ? L01 : L11;
            const unsigned int ko0 = hiq ? H10 : H00, so0 = hiq ? H00 : H10;
            const unsigned int ko1 = hiq ? H11 : H01, so1 = hiq ? H01 : H11;
            const unsigned int re0 = __shfl_xor(se0, 32), re1 = __shfl_xor(se1, 32);
            const unsigned int ro0 = __shfl_xor(so0, 32), ro1 = __shfl_xor(so1, 32);
            union { unsigned int u[4]; half8 h; } pk;
            pk.u[0] = own ? ke0 : re0;
            pk.u[1] = own ? ke1 : re1;
            pk.u[2] = own ? ko0 : ro0;
            pk.u[3] = own ? ko1 : ro1;
            pf0 = pk.h;
        }
        {   // batch 1: jt {2,3} -> pf1
            const unsigned int u00 = pack2h(sv[2][0], sv[2][1]);
            const unsigned int u01 = pack2h(sv[2][2], sv[2][3]);
            const unsigned int u10 = pack2h(sv[3][0], sv[3][1]);
            const unsigned int u11 = pack2h(sv[3][2], sv[3][3]);
            const unsigned int t00 = __shfl_xor(u00, 16), t01 = __shfl_xor(u01, 16);
            const unsigned int t10 = __shfl_xor(u10, 16), t11 = __shfl_xor(u11, 16);
            const unsigned int L00 = oddq ? t00 : u00, H00 = oddq ? u00 : t00;
            const unsigned int L01 = oddq ? t01 : u01, H01 = oddq ? u01 : t01;
            const unsigned int L10 = oddq ? t10 : u10, H10 = oddq ? u10 : t10;
            const unsigned int L11 = oddq ? t11 : u11, H11 = oddq ? u11 : t11;
            const unsigned int ke0 = hiq ? L10 : L00, se0 = hiq ? L00 : L10;
            const unsigned int ke1 = hiq ? L11 : L01, se1 = hiq ? L01 : L11;
            const unsigned int ko0 = hiq ? H10 : H00, so0 = hiq ? H00 : H10;
            const unsigned int ko1 = hiq ? H11 : H01, so1 = hiq ? H01 : H11;
            const unsigned int re0 = __shfl_xor(se0, 32), re1 = __shfl_xor(se1, 32);
            const unsigned int ro0 = __shfl_xor(so0, 32), ro1 = __shfl_xor(so1, 32);
            union { unsigned int u[4]; half8 h; } pk;
            pk.u[0] = own ? ke0 : re0;
            pk.u[1] = own ? ke1 : re1;
            pk.u[2] = own ? ko0 : ro0;
            pk.u[3] = own ? ko1 : ro1;
            pf1 = pk.h;
        }

        __syncthreads();   // B2: V(ti) visible; all waves done reading K(ti)

        // ---- stage K(ti+1) async (flies under PV-MFMAs)
        if (ti < NITER - 1) {
            const int lr = lane >> 5, cp = lane & 31;
#pragma unroll
            for (int p = 0; p < 8; p++) {
                const int jl = wave * 16 + p * 2 + lr;
                g2l16(Kb + (size_t)(j0 + 64 + jl) * C_DIM + (cp ^ (jl & 7)) * 8,
                      &Ks[(wave * 16 + p * 2) * 256]);
            }
        }

        // ---- O^T += V P^T
        __builtin_amdgcn_s_setprio(1);
#pragma unroll
        for (int ot = 0; ot < 16; ot++) {
            const int row = (ot * 16 + l15) * 64;
            const half8 av0 = *(const half8*)&Vs[row + ((quad ^ lk) * 8)];
            const half8 av1 = *(const half8*)&Vs[row + (((4 + quad) ^ lk) * 8)];
            oacc[ot] = __builtin_amdgcn_mfma_f32_16x16x32_f16(av0, pf0, oacc[ot], 0, 0, 0);
            oacc[ot] = __builtin_amdgcn_mfma_f32_16x16x32_f16(av1, pf1, oacc[ot], 0, 0, 0);
        }
        __builtin_amdgcn_s_setprio(0);
    }

    // ---- epilogue: unnormalized O^T fp16 + (m,l)
    unsigned short* Ob = Op + ((size_t)(s * 4 + b) * C_DIM) * N_TOK;
    const int n = qt * 64 + wave * 16 + l15;
#pragma unroll
    for (int ot = 0; ot < 16; ot++) {
#pragma unroll
        for (int r = 0; r < 4; r++) {
            const int c = ot * 16 + quad * 4 + r;
            Ob[(size_t)c * N_TOK + n] = f2h(oacc[ot][r]);
        }
    }
    float lt = l_i;
    lt += __shfl_xor(lt, 16);
    lt += __shfl_xor(lt, 32);
    if (quad == 0) {
        const size_t nb = (size_t)(s * 4 + b) * N_TOK + n;
        *(float2*)&Lm[nb * 2] = make_float2(m_i, lt);
    }
}

// ---------------------------------------------------------------------------
// merge_kernel: out = gamma * (sum_s w_s O_s) / (sum_s w_s l_s) + x
// ---------------------------------------------------------------------------
__global__ __launch_bounds__(256) void merge_kernel(
    const unsigned short* __restrict__ Op,
    const float* __restrict__ Lm,
    const float* __restrict__ x,
    const float* __restrict__ gamma,
    float* __restrict__ out)
{
    constexpr int NS = 2;
    const int blk = blockIdx.x;          // 4096
    const int b   = blk >> 10;
    const int c   = (blk >> 2) & 255;
    const int nq  = blk & 3;
    const int n0  = nq * 1024 + threadIdx.x * 4;

    const size_t NEo = (size_t)4 * C_DIM * N_TOK;
    const size_t obase = ((size_t)b * C_DIM + c) * N_TOK + n0;

    float ms[NS][4], ls[NS][4], os[NS][4];
#pragma unroll
    for (int s = 0; s < NS; s++) {
        const uint2 u = *(const uint2*)&Op[s * NEo + obase];
        os[s][0] = h2f((unsigned short)(u.x & 0xffff));
        os[s][1] = h2f((unsigned short)(u.x >> 16));
        os[s][2] = h2f((unsigned short)(u.y & 0xffff));
        os[s][3] = h2f((unsigned short)(u.y >> 16));
        const float* Lms = Lm + (size_t)(s * 4 + b) * N_TOK * 2;
        const float4 A0 = *(const float4*)&Lms[n0 * 2];
        const float4 A1 = *(const float4*)&Lms[n0 * 2 + 4];
        ms[s][0] = A0.x; ls[s][0] = A0.y;
        ms[s][1] = A0.z; ls[s][1] = A0.w;
        ms[s][2] = A1.x; ls[s][2] = A1.y;
        ms[s][3] = A1.z; ls[s][3] = A1.w;
    }
    const float4 xv = *(const float4*)&x[obase];
    const float xin[4] = {xv.x, xv.y, xv.z, xv.w};
    const float g = gamma[0];

    float4 res;
    float* rp = (float*)&res;
#pragma unroll
    for (int i = 0; i < 4; i++) {
        float M = ms[0][i];
#pragma unroll
        for (int s = 1; s < NS; s++) M = fmaxf(M, ms[s][i]);
        float osum = 0.f, lsum = 0.f;
#pragma unroll
        for (int s = 0; s < NS; s++) {
            const float w = __expf(ms[s][i] - M);
            osum += w * os[s][i];
            lsum += w * ls[s][i];
        }
        rp[i] = g * osum / lsum + xin[i];
    }
    *(float4*)&out[obase] = res;
}

extern "C" void kernel_launch(void* const* d_in, const int* in_sizes, int n_in,
                              void* d_out, int out_size, void* d_ws, size_t ws_size,
                              hipStream_t stream) {
    const float* x     = (const float*)d_in[0];
    const float* Wq    = (const float*)d_in[1];
    const float* bq    = (const float*)d_in[2];
    const float* Wk    = (const float*)d_in[3];
    const float* bk    = (const float*)d_in[4];
    const float* Wv    = (const float*)d_in[5];
    const float* bv    = (const float*)d_in[6];
    const float* relh  = (const float*)d_in[7];
    const float* relw  = (const float*)d_in[8];
    const float* gamma = (const float*)d_in[9];
    float* out = (float*)d_out;

    const size_t NE = (size_t)4 * N_TOK * C_DIM;   // 4.19M elems

    // Region layout (Op overlays Xhi/Xlo: X dead before flash writes Op)
    unsigned short* Op  = (unsigned short*)d_ws;           // 2*NE u16
    unsigned short* Xhi = Op;                              // NE u16 (prep/proj only)
    unsigned short* Xlo = Op + NE;                         // NE u16
    unsigned short* Whi = Op + (size_t)2 * NE;             // 3*65536 u16
    unsigned short* Wlo = Whi + 3 * 65536;
    unsigned short* Qh  = Wlo + 3 * 65536;                 // NE u16 (fp16)
    unsigned short* Kh  = Qh + NE;                         // NE u16 (fp16)
    unsigned short* Vh  = Kh + NE;                         // NE u16 (fp16)
    float* Lm = (float*)(Vh + NE);                         // 2*4*4096*2 floats

    hipLaunchKernelGGL(prep_kernel, dim3(1027), dim3(256), 0, stream,
                       x, Wq, Wk, Wv, Xhi, Xlo, Whi, Wlo);
    hipLaunchKernelGGL(proj_kernel, dim3(768), dim3(256), 0, stream,
                       Xhi, Xlo, Whi, Wlo, bq, bk, bv, relh, relw, Qh, Kh, Vh);
    hipLaunchKernelGGL(flash_kernel, dim3(512), dim3(256), 0, stream,
                       Qh, Kh, Vh, Op, Lm);
    hipLaunchKernelGGL(merge_kernel, dim3(4096), dim3(256), 0, stream,
                       Op, Lm, x, gamma, out);
}